// Round 5
// baseline (47.646 us; speedup 1.0000x reference)
//
#include <hip/hip_runtime.h>
#include <hip/hip_bf16.h>

#define LATENT 16
#define STATE  16
#define NPOS   (64 * 8192)
#define NTILES (NPOS / 16)        // 32768 tiles of 16 positions
#define NCHUNK 9                  // K = 288 = 9 * 32
#define TPW    4                  // tiles per wave

typedef __attribute__((ext_vector_type(4))) float f32x4;
typedef __attribute__((ext_vector_type(8))) short bf16x8;  // 8 bf16 in 4 VGPRs

static __device__ __forceinline__ short f2bf(float f) {
    __hip_bfloat16 h = __float2bfloat16(f);
    return (short)__builtin_bit_cast(unsigned short, h);
}

// ---------------- prep: pack W into MFMA B-fragment order ----------------
// ws layout: [0..15] f32 bias (const-term row); then 4608 ushort Wpack.
// Wpack[(c*64 + lane)*8 + jj] = bf16 W'[k = c*32 + (lane>>4)*8 + jj][col = lane&15]
// K order: k<256: x_I * x_J, I=k>>4, J=k&15 (off-diag weights halved);
//          k=256..271: linear x[k-256]; k=272..287: sin(x[k-272]).
__global__ __launch_bounds__(256) void prep_pack(const float* __restrict__ coef,
                                                 const float* __restrict__ mask,
                                                 float* __restrict__ wsf) {
    int id = blockIdx.x * 256 + threadIdx.x;
    if (id < 16) wsf[id] = coef[id] * mask[id];   // bias: ref row 0 (const)
    if (id >= 4608) return;
    int jj  = id & 7;
    int col = (id >> 3) & 15;
    int g   = (id >> 7) & 3;
    int c   = id >> 9;                    // 0..8
    int k   = c * 32 + g * 8 + jj;        // 0..287
    float scale = 1.0f;
    int row;
    if (k < 256) {
        int I = k >> 4, J = k & 15;
        int im = I < J ? I : J, jm = I < J ? J : I;
        int q = im * 16 - im * (im - 1) / 2 + (jm - im);  // comb_w_r index
        row = 17 + q;
        if (I != J) scale = 0.5f;
    } else if (k < 272) {
        row = 1 + (k - 256);
    } else {
        row = 153 + (k - 272);
    }
    float w = coef[row * STATE + col] * mask[row * STATE + col] * scale;
    ((ushort*)(wsf + 16))[id] = (ushort)f2bf(w);
}

// ---------------- main: theta-on-the-fly MFMA GEMM, no LDS ----------------
// Each lane loads its own A-row (row `col` of the tile) straight from global:
// addresses of the 16 cols are 256B contiguous per q; the 4-way duplication
// across g merges in the coalescer -> HBM traffic = exactly x once.
// NOTE rule #20: all register arrays indexed with compile-time constants only;
// runtime g-dependence handled by 16 cndmask selects per tile (xv/xi build).
__global__ __launch_bounds__(256) void sindy_mfma(const float* __restrict__ x,
                                                  const float* __restrict__ wsf,
                                                  float* __restrict__ out) {
    const int lane  = threadIdx.x & 63;
    const int wid   = threadIdx.x >> 6;
    const int g     = lane >> 4;          // K-slice group 0..3
    const int col   = lane & 15;          // A-row (position in tile) and D-col
    const bool hiJ  = (g & 1) != 0;       // J-half this lane multiplies
    const bool hiI  = (g >> 1) != 0;      // I parity this lane covers

    // B fragments: wave-wide resident, loaded once (9 x 16B per lane)
    const ushort* Wpack = (const ushort*)(wsf + 16);
    bf16x8 bfrag[NCHUNK];
    #pragma unroll
    for (int c = 0; c < NCHUNK; ++c)
        bfrag[c] = *(const bf16x8*)(Wpack + (c * 64 + lane) * 8);

    const float bias = wsf[col];

    const float4* x4 = (const float4*)x;
    const int wave_gid = blockIdx.x * 4 + wid;   // 8192 waves
    const int tile0 = wave_gid * TPW;

    float4 cur[4], nxt[4];
    #pragma unroll
    for (int q = 0; q < 4; ++q)
        cur[q] = x4[(long)(tile0 * 16 + col) * 4 + q];

    #pragma unroll
    for (int t = 0; t < TPW; ++t) {
        const int tile = tile0 + t;
        if (t < TPW - 1) {
            #pragma unroll
            for (int q = 0; q < 4; ++q)
                nxt[q] = x4[(long)((tile + 1) * 16 + col) * 4 + q];
        }

        // unpack row (compile-time indices only)
        float row[16];
        #pragma unroll
        for (int q = 0; q < 4; ++q) {
            row[q * 4 + 0] = cur[q].x; row[q * 4 + 1] = cur[q].y;
            row[q * 4 + 2] = cur[q].z; row[q * 4 + 3] = cur[q].w;
        }

        // per-lane operand vectors, built with selects (no runtime indexing)
        float xv[8], xi[8];
        #pragma unroll
        for (int j = 0; j < 8; ++j) xv[j] = hiJ ? row[8 + j] : row[j];
        #pragma unroll
        for (int c = 0; c < 8; ++c) xi[c] = hiI ? row[2 * c + 1] : row[2 * c];

        f32x4 acc = {bias, bias, bias, bias};

        // quad chunks: A[col][c*32 + g*8 + jj] = x[2c + hiI] * x[j0 + jj]
        #pragma unroll
        for (int c = 0; c < 8; ++c) {
            bf16x8 a;
            #pragma unroll
            for (int j = 0; j < 8; ++j) a[j] = f2bf(xi[c] * xv[j]);
            acc = __builtin_amdgcn_mfma_f32_16x16x32_bf16(a, bfrag[c], acc, 0, 0, 0);
        }
        // chunk 8: g<2 -> linear xv[j]; g>=2 -> sin(xv[j])
        {
            bf16x8 a;
            #pragma unroll
            for (int j = 0; j < 8; ++j) {
                float v = xv[j];
                float s = __sinf(v);
                a[j] = f2bf(g >= 2 ? s : v);
            }
            acc = __builtin_amdgcn_mfma_f32_16x16x32_bf16(a, bfrag[8], acc, 0, 0, 0);
        }

        // D: row = g*4 + r (position), col = state
        #pragma unroll
        for (int r = 0; r < 4; ++r)
            out[(long)(tile * 16 + g * 4 + r) * STATE + col] = acc[r];

        #pragma unroll
        for (int q = 0; q < 4; ++q) cur[q] = nxt[q];
    }
}

extern "C" void kernel_launch(void* const* d_in, const int* in_sizes, int n_in,
                              void* d_out, int out_size, void* d_ws, size_t ws_size,
                              hipStream_t stream) {
    const float* x    = (const float*)d_in[0];
    const float* coef = (const float*)d_in[1];
    const float* mask = (const float*)d_in[2];
    float*       wsf  = (float*)d_ws;     // 16 f32 bias + 4608 ushort Wpack
    float*       out  = (float*)d_out;

    prep_pack<<<18, 256, 0, stream>>>(coef, mask, wsf);
    sindy_mfma<<<NTILES / (4 * TPW), 256, 0, stream>>>(x, wsf, out);  // 2048 blocks
}

// Round 6
// 25.900 us; speedup vs baseline: 1.8396x; 1.8396x over previous
//
#include <hip/hip_runtime.h>
#include <hip/hip_bf16.h>

#define LATENT 16
#define STATE  16
#define NPOS   (64 * 8192)
#define NTILES (NPOS / 16)        // 32768 tiles of 16 positions
#define TPW    4                  // tiles per wave

typedef __attribute__((ext_vector_type(4))) float f32x4;
typedef __attribute__((ext_vector_type(8))) short bf16x8;  // 8 bf16 in 4 VGPRs

static __device__ __forceinline__ short f2bf(float f) {
    __hip_bfloat16 h = __float2bfloat16(f);
    return (short)__builtin_bit_cast(unsigned short, h);
}

// ---------------- prep: pack W into MFMA B-fragment order ----------------
// ws layout: [0..15] f32 bias (const-term row); then 4608 ushort Wpack.
// Wpack[(c*64 + lane)*8 + jj] = bf16 W'[k = c*32 + (lane>>4)*8 + jj][col = lane&15]
// K order: k<256: x_I * x_J, I=k>>4, J=k&15 (off-diag weights halved);
//          k=256..271: linear x[k-256]; k=272..287: sin(x[k-272]).
__global__ __launch_bounds__(256) void prep_pack(const float* __restrict__ coef,
                                                 const float* __restrict__ mask,
                                                 float* __restrict__ wsf) {
    int id = blockIdx.x * 256 + threadIdx.x;
    if (id < 16) wsf[id] = coef[id] * mask[id];   // bias: ref row 0 (const)
    if (id >= 4608) return;
    int jj  = id & 7;
    int col = (id >> 3) & 15;
    int g   = (id >> 7) & 3;
    int c   = id >> 9;                    // 0..8
    int k   = c * 32 + g * 8 + jj;        // 0..287
    float scale = 1.0f;
    int row;
    if (k < 256) {
        int I = k >> 4, J = k & 15;
        int im = I < J ? I : J, jm = I < J ? J : I;
        int q = im * 16 - im * (im - 1) / 2 + (jm - im);  // comb_w_r index
        row = 17 + q;
        if (I != J) scale = 0.5f;
    } else if (k < 272) {
        row = 1 + (k - 256);
    } else {
        row = 153 + (k - 272);
    }
    float w = coef[row * STATE + col] * mask[row * STATE + col] * scale;
    ((ushort*)(wsf + 16))[id] = (ushort)f2bf(w);
}

// ---------------- main: theta-on-the-fly MFMA GEMM, no LDS, no allocas ----
// RULE #20 discipline: zero C arrays. B-fragments, x-row, xv/xi are all
// NAMED SSA values; runtime g-dependence is value-level cndmask only, so
// PromoteAlloca/InstCombine cannot demote anything to scratch or LDS.
__global__ __launch_bounds__(256, 4) void sindy_mfma(const float* __restrict__ x,
                                                     const float* __restrict__ wsf,
                                                     float* __restrict__ out) {
    const int lane  = threadIdx.x & 63;
    const int wid   = threadIdx.x >> 6;
    const int g     = lane >> 4;          // K-slice group 0..3
    const int col   = lane & 15;          // A-row (position in tile) and D-col
    const bool hiJ  = (g & 1) != 0;       // J-half this lane multiplies
    const bool hiI  = (g >> 1) != 0;      // I parity this lane covers

    // B fragments: wave-wide resident, loaded once (9 x 16B per lane), NAMED
    const ushort* Wpack = (const ushort*)(wsf + 16);
    const bf16x8 b0 = *(const bf16x8*)(Wpack + (0 * 64 + lane) * 8);
    const bf16x8 b1 = *(const bf16x8*)(Wpack + (1 * 64 + lane) * 8);
    const bf16x8 b2 = *(const bf16x8*)(Wpack + (2 * 64 + lane) * 8);
    const bf16x8 b3 = *(const bf16x8*)(Wpack + (3 * 64 + lane) * 8);
    const bf16x8 b4 = *(const bf16x8*)(Wpack + (4 * 64 + lane) * 8);
    const bf16x8 b5 = *(const bf16x8*)(Wpack + (5 * 64 + lane) * 8);
    const bf16x8 b6 = *(const bf16x8*)(Wpack + (6 * 64 + lane) * 8);
    const bf16x8 b7 = *(const bf16x8*)(Wpack + (7 * 64 + lane) * 8);
    const bf16x8 b8 = *(const bf16x8*)(Wpack + (8 * 64 + lane) * 8);

    const float bias = wsf[col];
    const float4* x4 = (const float4*)x;

    const int wave_gid = blockIdx.x * 4 + wid;   // 8192 waves
    const int tile0 = wave_gid * TPW;
    const long base = (long)(tile0 * 16 + col) * 4;   // float4 index of my row

    // per-tile body: all operands are by-value SSA
    auto do_tile = [&](int tile, float4 A, float4 B, float4 C, float4 D) {
        // xv: the J-half this lane multiplies (value selects, not addresses)
        const float xv0 = hiJ ? C.x : A.x;
        const float xv1 = hiJ ? C.y : A.y;
        const float xv2 = hiJ ? C.z : A.z;
        const float xv3 = hiJ ? C.w : A.w;
        const float xv4 = hiJ ? D.x : B.x;
        const float xv5 = hiJ ? D.y : B.y;
        const float xv6 = hiJ ? D.z : B.z;
        const float xv7 = hiJ ? D.w : B.w;
        // xi: element 2c + hiI
        const float xi0 = hiI ? A.y : A.x;
        const float xi1 = hiI ? A.w : A.z;
        const float xi2 = hiI ? B.y : B.x;
        const float xi3 = hiI ? B.w : B.z;
        const float xi4 = hiI ? C.y : C.x;
        const float xi5 = hiI ? C.w : C.z;
        const float xi6 = hiI ? D.y : D.x;
        const float xi7 = hiI ? D.w : D.z;

        f32x4 acc = {bias, bias, bias, bias};

#define QUAD(BF, XI)                                                     \
        {                                                                \
            bf16x8 af;                                                   \
            af[0] = f2bf((XI) * xv0); af[1] = f2bf((XI) * xv1);          \
            af[2] = f2bf((XI) * xv2); af[3] = f2bf((XI) * xv3);          \
            af[4] = f2bf((XI) * xv4); af[5] = f2bf((XI) * xv5);          \
            af[6] = f2bf((XI) * xv6); af[7] = f2bf((XI) * xv7);          \
            acc = __builtin_amdgcn_mfma_f32_16x16x32_bf16(af, BF, acc, 0, 0, 0); \
        }
        QUAD(b0, xi0) QUAD(b1, xi1) QUAD(b2, xi2) QUAD(b3, xi3)
        QUAD(b4, xi4) QUAD(b5, xi5) QUAD(b6, xi6) QUAD(b7, xi7)
#undef QUAD
        // chunk 8: g<2 -> linear xv; g>=2 -> sin(xv)
        {
            const bool us = (g >= 2);
            bf16x8 af;
            af[0] = f2bf(us ? __sinf(xv0) : xv0);
            af[1] = f2bf(us ? __sinf(xv1) : xv1);
            af[2] = f2bf(us ? __sinf(xv2) : xv2);
            af[3] = f2bf(us ? __sinf(xv3) : xv3);
            af[4] = f2bf(us ? __sinf(xv4) : xv4);
            af[5] = f2bf(us ? __sinf(xv5) : xv5);
            af[6] = f2bf(us ? __sinf(xv6) : xv6);
            af[7] = f2bf(us ? __sinf(xv7) : xv7);
            acc = __builtin_amdgcn_mfma_f32_16x16x32_bf16(af, b8, acc, 0, 0, 0);
        }

        // D: row = g*4 + r (position), col = state
        const long obase = (long)(tile * 16 + g * 4) * STATE + col;
        out[obase + 0 * STATE] = acc[0];
        out[obase + 1 * STATE] = acc[1];
        out[obase + 2 * STATE] = acc[2];
        out[obase + 3 * STATE] = acc[3];
    };

    float4 c0 = x4[base + 0], c1 = x4[base + 1],
           c2 = x4[base + 2], c3 = x4[base + 3];
    #pragma unroll
    for (int t = 0; t < TPW; ++t) {
        float4 n0 = c0, n1 = c1, n2 = c2, n3 = c3;
        if (t < TPW - 1) {                 // prefetch next tile's row
            const long nb = base + (long)(t + 1) * 64;
            n0 = x4[nb + 0]; n1 = x4[nb + 1];
            n2 = x4[nb + 2]; n3 = x4[nb + 3];
        }
        do_tile(tile0 + t, c0, c1, c2, c3);
        c0 = n0; c1 = n1; c2 = n2; c3 = n3;
    }
}

extern "C" void kernel_launch(void* const* d_in, const int* in_sizes, int n_in,
                              void* d_out, int out_size, void* d_ws, size_t ws_size,
                              hipStream_t stream) {
    const float* x    = (const float*)d_in[0];
    const float* coef = (const float*)d_in[1];
    const float* mask = (const float*)d_in[2];
    float*       wsf  = (float*)d_ws;     // 16 f32 bias + 4608 ushort Wpack
    float*       out  = (float*)d_out;

    prep_pack<<<18, 256, 0, stream>>>(coef, mask, wsf);
    sindy_mfma<<<NTILES / (4 * TPW), 256, 0, stream>>>(x, wsf, out);  // 2048 blocks
}